// Round 4
// baseline (332.166 us; speedup 1.0000x reference)
//
#include <hip/hip_runtime.h>
#include <hip/hip_bf16.h>
#include <math.h>

#define ROWS 256
#define DD 64
#define EE 8
#define HH 64
#define GH 32

typedef __attribute__((ext_vector_type(8))) short bf16x8;
typedef __attribute__((ext_vector_type(4))) float f32x4;
typedef __attribute__((ext_vector_type(2))) float f32x2;

static __device__ __forceinline__ short f2bf(float f) {
    unsigned u = __builtin_bit_cast(unsigned, f);
    unsigned r = (u + 0x7fffu + ((u >> 16) & 1u)) >> 16;  // round-to-nearest-even
    return (short)r;
}
static __device__ __forceinline__ float bf2f(unsigned short b) {
    unsigned u = ((unsigned)b) << 16;
    return __builtin_bit_cast(float, u);
}
// pack 2 f32 -> 2 bf16 (RNE); use HW packed cvt if present
static __device__ __forceinline__ unsigned pk2bf(float a, float b) {
#if __has_builtin(__builtin_amdgcn_cvt_pk_bf16_f32)
    typedef __attribute__((ext_vector_type(2))) __bf16 bf16x2_t;
    bf16x2_t v = __builtin_amdgcn_cvt_pk_bf16_f32(a, b);
    return __builtin_bit_cast(unsigned, v);
#else
    return ((unsigned)(unsigned short)f2bf(a)) | (((unsigned)(unsigned short)f2bf(b)) << 16);
#endif
}
// butterfly add via DPP (ctrl must be a compile-time constant)
template <int CTRL>
static __device__ __forceinline__ float dpp_add(float x) {
    int xi = __builtin_bit_cast(int, x);
    int yi = __builtin_amdgcn_update_dpp(0, xi, CTRL, 0xF, 0xF, true);
    return x + __builtin_bit_cast(float, yi);
}

// Precompute W1 as bf16 MFMA B-fragments in d_ws.
// layout: frag index idx = wave<<10 | tt<<7 | half<<6 | lane, 8 shorts each (64 KB)
__global__ __launch_bounds__(256) void prep_kernel(const float* __restrict__ ew1,
                                                   short* __restrict__ wf) {
    int idx = blockIdx.x * 256 + threadIdx.x;   // 4096 frags
    int lane = idx & 63;
    int half = (idx >> 6) & 1;
    int tt   = (idx >> 7) & 7;
    int wave = (idx >> 10) & 3;
    int n = wave * 128 + tt * 16 + (lane & 15);
    int e = n >> 6, h = n & 63;
    int quad = lane >> 4;
    short v[8];
    #pragma unroll
    for (int j = 0; j < 8; ++j) {
        int dl = quad * 8 + j + half * 32;
        v[j] = f2bf(ew1[(e * DD + dl) * HH + h]);
    }
    *(bf16x8*)(wf + (size_t)idx * 8) = *(const bf16x8*)v;
}

__global__ __launch_bounds__(256, 4) void moe_kernel(
    const float* __restrict__ A, const float* __restrict__ S,
    const float* __restrict__ gw1, const float* __restrict__ gb1,
    const float* __restrict__ gw2, const float* __restrict__ gb2,
    const short* __restrict__ wf,  const float* __restrict__ eb1,
    const float* __restrict__ ew2, const float* __restrict__ eb2,
    float* __restrict__ out)
{
    // xs row = 72 shorts (144 B): [0..63] bf16 x-data, [64..65] = rowsum (f32), rest pad.
    // stride = 36 words: rows lr and lr+8 alias banks 2-way only (free per m136).
    __shared__ short xs[ROWS][72];                 // 36864 B
    __shared__ unsigned short psb[ROWS][EE];       // 4096 B  (bf16 gating probs)
    // total 40960 B

    const int t = threadIdx.x;
    const int row0 = blockIdx.x * ROWS;
    const int lane = t & 63;
    const int wave = t >> 6;
    const int quad = lane >> 4;
    const int lr = lane & 15;

    float extra;  // per-thread eb2 term for its own row

    // ---- Phase 1: per-thread gating (packed f32) + x -> LDS (bf16) ----
    {
        const int row = row0 + t;
        const float* arow = A + (size_t)row * 32;
        const float* srow = S + (size_t)row * 32;
        float s[32];
        #pragma unroll
        for (int i = 0; i < 4; ++i) {
            float4 v0 = ((const float4*)arow)[2 * i];
            float4 v1 = ((const float4*)arow)[2 * i + 1];
            unsigned p0 = pk2bf(v0.x, v0.y), p1 = pk2bf(v0.z, v0.w);
            unsigned p2 = pk2bf(v1.x, v1.y), p3 = pk2bf(v1.z, v1.w);
            uint4 pk = {p0, p1, p2, p3};
            *(uint4*)&xs[t][i * 8] = pk;
        }
        #pragma unroll
        for (int i = 0; i < 4; ++i) {
            float4 v0 = ((const float4*)srow)[2 * i];
            float4 v1 = ((const float4*)srow)[2 * i + 1];
            s[i*8+0] = v0.x; s[i*8+1] = v0.y; s[i*8+2] = v0.z; s[i*8+3] = v0.w;
            s[i*8+4] = v1.x; s[i*8+5] = v1.y; s[i*8+6] = v1.z; s[i*8+7] = v1.w;
            unsigned p0 = pk2bf(v0.x, v0.y), p1 = pk2bf(v0.z, v0.w);
            unsigned p2 = pk2bf(v1.x, v1.y), p3 = pk2bf(v1.z, v1.w);
            uint4 pk = {p0, p1, p2, p3};
            *(uint4*)&xs[t][32 + i * 8] = pk;
        }
        *(float*)&xs[t][64] = 0.0f;   // rowsum init (lives in the row pad)

        // gating layer 1: [32] x [32x32] -> 16 f32x2 accumulators (v_pk_fma_f32)
        const f32x2* gw1v = (const f32x2*)gw1;
        f32x2 hacc[GH / 2];
        #pragma unroll
        for (int g = 0; g < GH / 2; ++g) hacc[g] = ((const f32x2*)gb1)[g];
        #pragma unroll
        for (int d = 0; d < 32; ++d) {
            f32x2 sv = {s[d], s[d]};
            #pragma unroll
            for (int g = 0; g < GH / 2; ++g)
                hacc[g] = __builtin_elementwise_fma(sv, gw1v[d * (GH / 2) + g], hacc[g]);
        }
        #pragma unroll
        for (int g = 0; g < GH / 2; ++g)
            hacc[g] = __builtin_elementwise_max(hacc[g], (f32x2){0.f, 0.f});

        // gating layer 2: [32] x [32x8] -> 4 f32x2 logit pairs
        const f32x2* gw2v = (const f32x2*)gw2;
        f32x2 lg2[EE / 2];
        #pragma unroll
        for (int ep = 0; ep < EE / 2; ++ep) lg2[ep] = ((const f32x2*)gb2)[ep];
        const float* hv = (const float*)hacc;
        #pragma unroll
        for (int g = 0; g < GH; ++g) {
            f32x2 hs = {hv[g], hv[g]};
            #pragma unroll
            for (int ep = 0; ep < EE / 2; ++ep)
                lg2[ep] = __builtin_elementwise_fma(hs, gw2v[g * (EE / 2) + ep], lg2[ep]);
        }
        const float* lg = (const float*)lg2;
        float mx = lg[0];
        #pragma unroll
        for (int e = 1; e < EE; ++e) mx = fmaxf(mx, lg[e]);
        float sum = 0.f, pv[EE];
        #pragma unroll
        for (int e = 0; e < EE; ++e) { pv[e] = expf(lg[e] - mx); sum += pv[e]; }
        float inv = 1.0f / sum;
        extra = 0.f;
        unsigned pb[EE / 2];
        #pragma unroll
        for (int e = 0; e < EE; e += 2) {
            float pa = pv[e] * inv, pbv = pv[e + 1] * inv;
            extra = fmaf(pa, eb2[e], extra);
            extra = fmaf(pbv, eb2[e + 1], extra);
            pb[e / 2] = pk2bf(pa, pbv);
        }
        uint4 pk = {pb[0], pb[1], pb[2], pb[3]};
        *(uint4*)&psb[t][0] = pk;
    }

    // ---- Load B fragments (precomputed bf16) + per-column w2/b1 ----
    bf16x8 blo[8], bhi[8];
    float w2p[8], b1c[8];
    const int e0 = wave * 2;
    #pragma unroll
    for (int tt = 0; tt < 8; ++tt) {
        const short* base = wf + ((size_t)((wave * 8 + tt) * 128) + lane) * 8;
        blo[tt] = *(const bf16x8*)base;
        bhi[tt] = *(const bf16x8*)(base + 512);
        int n = wave * 128 + tt * 16 + lr;
        int e = n >> 6, h = n & 63;
        w2p[tt] = ew2[e * HH + h];
        b1c[tt] = eb1[e * HH + h];
    }

    __syncthreads();

    // ---- Phase 2: MFMA over 16-row tiles ----
    #pragma unroll 1
    for (int rt = 0; rt < ROWS / 16; ++rt) {
        const short* xp = &xs[rt * 16 + lr][quad * 8];
        bf16x8 alo = *(const bf16x8*)xp;          // A[m=lr][k=quad*8+j], k in [0,32)
        bf16x8 ahi = *(const bf16x8*)(xp + 32);   // k in [32,64)
        f32x4 acc[8];
        #pragma unroll
        for (int tt = 0; tt < 8; ++tt)            // bias pre-folded into acc init
            acc[tt] = (f32x4){b1c[tt], b1c[tt], b1c[tt], b1c[tt]};
        #pragma unroll
        for (int tt = 0; tt < 8; ++tt)
            acc[tt] = __builtin_amdgcn_mfma_f32_16x16x32_bf16(alo, blo[tt], acc[tt], 0, 0, 0);
        #pragma unroll
        for (int tt = 0; tt < 8; ++tt)
            acc[tt] = __builtin_amdgcn_mfma_f32_16x16x32_bf16(ahi, bhi[tt], acc[tt], 0, 0, 0);

        // epilogue: relu (packed), fold w2 (packed fma), per-expert partials
        f32x2 q0[2] = {{0,0},{0,0}}, q1[2] = {{0,0},{0,0}};
        #pragma unroll
        for (int tt = 0; tt < 8; ++tt) {
            f32x2 w2s = {w2p[tt], w2p[tt]};
            const f32x2* ah = (const f32x2*)&acc[tt];
            #pragma unroll
            for (int h2 = 0; h2 < 2; ++h2) {
                f32x2 v = __builtin_elementwise_max(ah[h2], (f32x2){0.f, 0.f});
                if (tt < 4) q0[h2] = __builtin_elementwise_fma(v, w2s, q0[h2]);
                else        q1[h2] = __builtin_elementwise_fma(v, w2s, q1[h2]);
            }
        }
        const float* pe0 = (const float*)q0;
        const float* pe1 = (const float*)q1;
        #pragma unroll
        for (int r = 0; r < 4; ++r) {
            int rw = rt * 16 + quad * 4 + r;      // C/D row = quad*4+reg
            float c = pe0[r] * bf2f(psb[rw][e0]) + pe1[r] * bf2f(psb[rw][e0 + 1]);
            // butterfly over the 16 lanes of this quad-row group (DPP, VALU pipe)
            c = dpp_add<0xB1>(c);                 // quad_perm [1,0,3,2]  (xor 1)
            c = dpp_add<0x4E>(c);                 // quad_perm [2,3,0,1]  (xor 2)
            c = dpp_add<0x124>(c);                // row_ror:4
            c = dpp_add<0x128>(c);                // row_ror:8
            if (lr == 0) atomicAdd((float*)&xs[rw][64], c);
        }
    }

    __syncthreads();
    out[row0 + t] = *(const float*)&xs[t][64] + extra;
}

extern "C" void kernel_launch(void* const* d_in, const int* in_sizes, int n_in,
                              void* d_out, int out_size, void* d_ws, size_t ws_size,
                              hipStream_t stream) {
    const float* A   = (const float*)d_in[0];
    const float* S   = (const float*)d_in[1];
    const float* gw1 = (const float*)d_in[2];
    const float* gb1 = (const float*)d_in[3];
    const float* gw2 = (const float*)d_in[4];
    const float* gb2 = (const float*)d_in[5];
    const float* ew1 = (const float*)d_in[6];
    const float* eb1 = (const float*)d_in[7];
    const float* ew2 = (const float*)d_in[8];
    const float* eb2 = (const float*)d_in[9];
    float* out = (float*)d_out;
    short* wf = (short*)d_ws;   // 64 KB of bf16 W1 fragments

    const int B = in_sizes[0] / 32;
    hipLaunchKernelGGL(prep_kernel, dim3(16), dim3(256), 0, stream, ew1, wf);
    hipLaunchKernelGGL(moe_kernel, dim3(B / ROWS), dim3(256), 0, stream,
                       A, S, gw1, gb1, gw2, gb2, wf, eb1, ew2, eb2, out);
}